// Round 1
// baseline (1417.574 us; speedup 1.0000x reference)
//
#include <hip/hip_runtime.h>
#include <math.h>

#define NN 100000
#define NE 1600000

// ---------------- CSR build ----------------

__global__ void count_kernel(const int* __restrict__ ei, int* __restrict__ cnt,
                             int E, int n) {
    int e = blockIdx.x * 256 + threadIdx.x;
    if (e < E) {
        int d = ei[E + e];
        if ((unsigned)d < (unsigned)n) atomicAdd(&cnt[d], 1);
    }
}

__global__ void dinv_kernel(const int* __restrict__ cnt, float* __restrict__ dinv, int n) {
    int i = blockIdx.x * 256 + threadIdx.x;
    if (i < n) dinv[i] = 1.0f / sqrtf((float)cnt[i] + 1.0f);
}

// single-block exclusive scan over n counts -> rowptr[0..n]
__global__ void scan_kernel(const int* __restrict__ cnt, int* __restrict__ rowptr, int n) {
    __shared__ int sums[1024];
    int t = threadIdx.x;
    int chunk = (n + 1023) >> 10;
    int beg = t * chunk;
    int end = min(beg + chunk, n);
    int s = 0;
    for (int i = beg; i < end; i++) s += cnt[i];
    sums[t] = s;
    __syncthreads();
    for (int off = 1; off < 1024; off <<= 1) {
        int v = (t >= off) ? sums[t - off] : 0;
        __syncthreads();
        sums[t] += v;
        __syncthreads();
    }
    int run = (t == 0) ? 0 : sums[t - 1];
    for (int i = beg; i < end; i++) { rowptr[i] = run; run += cnt[i]; }
    if (beg < n && end == n) rowptr[n] = run;
}

__global__ void fill_kernel(const int* __restrict__ ei, const int* __restrict__ rowptr,
                            int* __restrict__ fill, int* __restrict__ colid, int E, int n) {
    int e = blockIdx.x * 256 + threadIdx.x;
    if (e < E) {
        int s = ei[e];
        int d = ei[E + e];
        if ((unsigned)d < (unsigned)n) {
            int pos = atomicAdd(&fill[d], 1);
            if ((unsigned)s >= (unsigned)n) s = 0;
            colid[rowptr[d] + pos] = s;
        }
    }
}

// ---------------- concat helpers ----------------

// A[n][160] = [feature[n][128] | condition[n][32]]   (float4 granularity)
__global__ void concat_kernel(const float4* __restrict__ f, const float4* __restrict__ c,
                              float4* __restrict__ A, int n) {
    int i = blockIdx.x * 256 + threadIdx.x;
    int total = n * 40;
    if (i < total) {
        int row = i / 40, j = i % 40;
        A[i] = (j < 32) ? f[row * 32 + j] : c[row * 8 + (j - 32)];
    }
}

// A[n][96] cols 64..95 = condition
__global__ void condcopy_kernel(const float4* __restrict__ c, float4* __restrict__ A, int n) {
    int i = blockIdx.x * 256 + threadIdx.x;
    if (i < n * 8) {
        int row = i / 8, j = i % 8;
        A[row * 24 + 16 + j] = c[row * 8 + j];
    }
}

// ---------------- GEMM: Y[n][OUT] = (X[n][K] @ W[K][OUT]) * dinv[row] ----------------
// block = 256 threads, tile = 64 rows x OUT cols, K-tile = 32.
// thread (tx=t&15, ty=t>>4) computes 4 rows x (4 or 8) cols.

template <int OUT>
__global__ __launch_bounds__(256)
void gemm_kernel(const float* __restrict__ X, int ldx, int K,
                 const float* __restrict__ W,
                 const float* __restrict__ dinv,
                 float* __restrict__ Y, int n) {
    constexpr int TN = (OUT == 128) ? 8 : 4;
    __shared__ float As[32][64];
    __shared__ float Bs[32][OUT];
    const int t = threadIdx.x;
    const int tx = t & 15;
    const int ty = t >> 4;
    const int row0 = blockIdx.x * 64;

    float acc[4][TN];
#pragma unroll
    for (int r = 0; r < 4; r++)
#pragma unroll
        for (int c = 0; c < TN; c++) acc[r][c] = 0.f;

    const int ar = t >> 3;         // 0..31
    const int ak = (t & 7) << 2;   // 0,4,...,28

    for (int kt = 0; kt < K; kt += 32) {
        // A tile: 64 rows x 32 k
#pragma unroll
        for (int i = 0; i < 2; i++) {
            int rr = ar + i * 32;
            int rg = row0 + rr;
            float4 v = make_float4(0.f, 0.f, 0.f, 0.f);
            if (rg < n) v = *(const float4*)(X + (size_t)rg * ldx + kt + ak);
            As[ak + 0][rr] = v.x; As[ak + 1][rr] = v.y;
            As[ak + 2][rr] = v.z; As[ak + 3][rr] = v.w;
        }
        // B tile: 32 k x OUT
        constexpr int F4 = OUT / 4;
#pragma unroll
        for (int it = 0; it < (32 * F4) / 256; it++) {
            int idx = t + it * 256;
            int kr = idx / F4, c4 = (idx % F4) * 4;
            *(float4*)&Bs[kr][c4] = *(const float4*)(W + (size_t)(kt + kr) * OUT + c4);
        }
        __syncthreads();
#pragma unroll 4
        for (int k = 0; k < 32; k++) {
            const float4 a = *(const float4*)&As[k][ty << 2];
            const float4 b0 = *(const float4*)&Bs[k][tx << 2];
            float av[4] = {a.x, a.y, a.z, a.w};
            float bv[TN];
            bv[0] = b0.x; bv[1] = b0.y; bv[2] = b0.z; bv[3] = b0.w;
            if constexpr (OUT == 128) {
                const float4 b1 = *(const float4*)&Bs[k][64 + (tx << 2)];
                bv[4] = b1.x; bv[5] = b1.y; bv[6] = b1.z; bv[7] = b1.w;
            }
#pragma unroll
            for (int r = 0; r < 4; r++)
#pragma unroll
                for (int c = 0; c < TN; c++)
                    acc[r][c] = fmaf(av[r], bv[c], acc[r][c]);
        }
        __syncthreads();
    }
#pragma unroll
    for (int r = 0; r < 4; r++) {
        int rg = row0 + (ty << 2) + r;
        if (rg < n) {
            float di = dinv[rg];
            float4 o0 = make_float4(acc[r][0] * di, acc[r][1] * di,
                                    acc[r][2] * di, acc[r][3] * di);
            *(float4*)(Y + (size_t)rg * OUT + (tx << 2)) = o0;
            if constexpr (OUT == 128) {
                float4 o1 = make_float4(acc[r][4] * di, acc[r][5] * di,
                                        acc[r][6] * di, acc[r][7] * di);
                *(float4*)(Y + (size_t)rg * OUT + 64 + (tx << 2)) = o1;
            }
        }
    }
}

// ---------------- propagation: out = dinv[i]*(sum_{src->i} hs[src] + hs[i]) + b ----------------
// one wave per node; lane holds 2 cols (OUT=128) or 1 col (OUT=64)

template <int OUT, bool TANH>
__global__ __launch_bounds__(256)
void prop_kernel(const float* __restrict__ hs, const float* __restrict__ dinv,
                 const int* __restrict__ rowptr, const int* __restrict__ colid,
                 const float* __restrict__ bias,
                 float* __restrict__ out, int ldo, int n) {
    int wave = threadIdx.x >> 6;
    int lane = threadIdx.x & 63;
    int node = blockIdx.x * 4 + wave;
    if (node >= n) return;
    int beg = rowptr[node], end = rowptr[node + 1];

    if constexpr (OUT == 128) {
        const float2* base = (const float2*)hs;
        float2 acc = base[(size_t)node * 64 + lane];  // self term (already *dinv[node])
        int e = beg;
        for (; e + 4 <= end; e += 4) {
            int s0 = colid[e], s1 = colid[e + 1], s2 = colid[e + 2], s3 = colid[e + 3];
            float2 v0 = base[(size_t)s0 * 64 + lane];
            float2 v1 = base[(size_t)s1 * 64 + lane];
            float2 v2 = base[(size_t)s2 * 64 + lane];
            float2 v3 = base[(size_t)s3 * 64 + lane];
            acc.x += v0.x + v1.x; acc.y += v0.y + v1.y;
            acc.x += v2.x + v3.x; acc.y += v2.y + v3.y;
        }
        for (; e < end; e++) {
            int s = colid[e];
            float2 v = base[(size_t)s * 64 + lane];
            acc.x += v.x; acc.y += v.y;
        }
        float di = dinv[node];
        float ox = di * acc.x + bias[2 * lane];
        float oy = di * acc.y + bias[2 * lane + 1];
        if (TANH) { ox = tanhf(ox); oy = tanhf(oy); }
        *(float2*)(out + (size_t)node * ldo + 2 * lane) = make_float2(ox, oy);
    } else {  // OUT == 64
        float acc = hs[(size_t)node * 64 + lane];
        int e = beg;
        for (; e + 4 <= end; e += 4) {
            int s0 = colid[e], s1 = colid[e + 1], s2 = colid[e + 2], s3 = colid[e + 3];
            acc += hs[(size_t)s0 * 64 + lane] + hs[(size_t)s1 * 64 + lane] +
                   hs[(size_t)s2 * 64 + lane] + hs[(size_t)s3 * 64 + lane];
        }
        for (; e < end; e++) acc += hs[(size_t)colid[e] * 64 + lane];
        float v = dinv[node] * acc + bias[lane];
        if (TANH) v = tanhf(v);
        out[(size_t)node * ldo + lane] = v;
    }
}

// ---------------- launch ----------------

extern "C" void kernel_launch(void* const* d_in, const int* in_sizes, int n_in,
                              void* d_out, int out_size, void* d_ws, size_t ws_size,
                              hipStream_t stream) {
    const int n = NN, E = NE;
    const float* feature   = (const float*)d_in[0];
    const float* condition = (const float*)d_in[1];
    const int*   ei        = (const int*)d_in[2];
    const float* W_e1 = (const float*)d_in[3];  const float* b_e1 = (const float*)d_in[4];
    const float* W_e2 = (const float*)d_in[5];  const float* b_e2 = (const float*)d_in[6];
    const float* W_e3 = (const float*)d_in[7];  const float* b_e3 = (const float*)d_in[8];
    const float* W_d1 = (const float*)d_in[9];  const float* b_d1 = (const float*)d_in[10];
    const float* W_d2 = (const float*)d_in[11]; const float* b_d2 = (const float*)d_in[12];
    const float* W_d3 = (const float*)d_in[13]; const float* b_d3 = (const float*)d_in[14];
    float* out = (float*)d_out;

    // workspace layout
    float* A    = (float*)d_ws;                 // n*160 floats (64 MB)
    float* B    = A + (size_t)n * 160;          // n*128 floats (51.2 MB)
    float* dinv = B + (size_t)n * 128;          // n floats
    int* cnt    = (int*)(dinv + n);             // n
    int* rowptr = cnt + n;                      // n+1
    int* fill   = rowptr + n + 1;               // n
    int* colid  = fill + n;                     // E

    hipMemsetAsync(cnt, 0, n * sizeof(int), stream);
    hipMemsetAsync(fill, 0, n * sizeof(int), stream);

    int eb = (E + 255) / 256;
    count_kernel<<<eb, 256, 0, stream>>>(ei, cnt, E, n);
    dinv_kernel<<<(n + 255) / 256, 256, 0, stream>>>(cnt, dinv, n);
    scan_kernel<<<1, 1024, 0, stream>>>(cnt, rowptr, n);
    fill_kernel<<<eb, 256, 0, stream>>>(ei, rowptr, fill, colid, E, n);

    concat_kernel<<<(n * 40 + 255) / 256, 256, 0, stream>>>(
        (const float4*)feature, (const float4*)condition, (float4*)A, n);

    int gt = (n + 63) / 64;
    int pb = (n + 3) / 4;

    // encoder
    gemm_kernel<128><<<gt, 256, 0, stream>>>(A, 160, 160, W_e1, dinv, B, n);
    prop_kernel<128, true><<<pb, 256, 0, stream>>>(B, dinv, rowptr, colid, b_e1, A, 128, n);
    gemm_kernel<128><<<gt, 256, 0, stream>>>(A, 128, 128, W_e2, dinv, B, n);
    prop_kernel<128, true><<<pb, 256, 0, stream>>>(B, dinv, rowptr, colid, b_e2, A, 128, n);
    gemm_kernel<64><<<gt, 256, 0, stream>>>(A, 128, 128, W_e3, dinv, B, n);
    prop_kernel<64, false><<<pb, 256, 0, stream>>>(B, dinv, rowptr, colid, b_e3, A, 96, n);
    condcopy_kernel<<<(n * 8 + 255) / 256, 256, 0, stream>>>(
        (const float4*)condition, (float4*)A, n);

    // decoder
    gemm_kernel<128><<<gt, 256, 0, stream>>>(A, 96, 96, W_d1, dinv, B, n);
    prop_kernel<128, true><<<pb, 256, 0, stream>>>(B, dinv, rowptr, colid, b_d1, A, 128, n);
    gemm_kernel<128><<<gt, 256, 0, stream>>>(A, 128, 128, W_d2, dinv, B, n);
    prop_kernel<128, true><<<pb, 256, 0, stream>>>(B, dinv, rowptr, colid, b_d2, A, 128, n);
    gemm_kernel<128><<<gt, 256, 0, stream>>>(A, 128, 128, W_d3, dinv, B, n);
    prop_kernel<128, false><<<pb, 256, 0, stream>>>(B, dinv, rowptr, colid, b_d3, out, 128, n);
}

// Round 2
// 1254.445 us; speedup vs baseline: 1.1300x; 1.1300x over previous
//
#include <hip/hip_runtime.h>
#include <math.h>

#define NN 100000
#define NE 1600000

// ---------------- CSR build ----------------

__global__ void count_kernel(const int* __restrict__ ei, int* __restrict__ cnt,
                             int E, int n) {
    int e = blockIdx.x * 256 + threadIdx.x;
    if (e < E) {
        int d = ei[E + e];
        if ((unsigned)d < (unsigned)n) atomicAdd(&cnt[d], 1);
    }
}

__global__ void dinv_kernel(const int* __restrict__ cnt, float* __restrict__ dinv, int n) {
    int i = blockIdx.x * 256 + threadIdx.x;
    if (i < n) dinv[i] = 1.0f / sqrtf((float)cnt[i] + 1.0f);
}

// ---- hierarchical exclusive scan: cnt[0..n) -> rowptr[0..n] ----
// pass 1: per-block (1024 elems) sums
__global__ __launch_bounds__(256)
void scan_blocksum(const int* __restrict__ cnt, int* __restrict__ bsum, int n) {
    __shared__ int red[256];
    int t = threadIdx.x;
    int base = blockIdx.x * 1024 + t * 4;
    int s = 0;
    if (base + 3 < n) {
        int4 v = *(const int4*)(cnt + base);
        s = v.x + v.y + v.z + v.w;
    } else {
        for (int j = 0; j < 4; j++) if (base + j < n) s += cnt[base + j];
    }
    red[t] = s;
    __syncthreads();
    for (int off = 128; off > 0; off >>= 1) {
        if (t < off) red[t] += red[t + off];
        __syncthreads();
    }
    if (t == 0) bsum[blockIdx.x] = red[0];
}

// pass 2: scan the (<=128) partials in one block; also write rowptr[n]=total
__global__ void scan_partials(int* __restrict__ bsum, int* __restrict__ rowptr,
                              int nb, int n) {
    __shared__ int sh[128];
    int t = threadIdx.x;  // 128 threads
    int v = (t < nb) ? bsum[t] : 0;
    sh[t] = v;
    __syncthreads();
    for (int off = 1; off < 128; off <<= 1) {
        int u = (t >= off) ? sh[t - off] : 0;
        __syncthreads();
        sh[t] += u;
        __syncthreads();
    }
    if (t < nb) bsum[t] = (t == 0) ? 0 : sh[t - 1];
    if (t == 0) rowptr[n] = sh[nb - 1];
}

// pass 3: per-block re-scan with offset -> rowptr
__global__ __launch_bounds__(256)
void scan_final(const int* __restrict__ cnt, const int* __restrict__ bsum,
                int* __restrict__ rowptr, int n) {
    __shared__ int sh[256];
    int t = threadIdx.x;
    int base = blockIdx.x * 1024 + t * 4;
    int v0 = 0, v1 = 0, v2 = 0, v3 = 0;
    if (base + 3 < n) {
        int4 v = *(const int4*)(cnt + base);
        v0 = v.x; v1 = v.y; v2 = v.z; v3 = v.w;
    } else {
        if (base < n)     v0 = cnt[base];
        if (base + 1 < n) v1 = cnt[base + 1];
        if (base + 2 < n) v2 = cnt[base + 2];
        if (base + 3 < n) v3 = cnt[base + 3];
    }
    sh[t] = v0 + v1 + v2 + v3;
    __syncthreads();
    for (int off = 1; off < 256; off <<= 1) {
        int u = (t >= off) ? sh[t - off] : 0;
        __syncthreads();
        sh[t] += u;
        __syncthreads();
    }
    int o = bsum[blockIdx.x] + ((t == 0) ? 0 : sh[t - 1]);
    if (base < n)     rowptr[base]     = o;
    if (base + 1 < n) rowptr[base + 1] = o + v0;
    if (base + 2 < n) rowptr[base + 2] = o + v0 + v1;
    if (base + 3 < n) rowptr[base + 3] = o + v0 + v1 + v2;
}

__global__ void fill_kernel(const int* __restrict__ ei, const int* __restrict__ rowptr,
                            int* __restrict__ fill, int* __restrict__ colid, int E, int n) {
    int e = blockIdx.x * 256 + threadIdx.x;
    if (e < E) {
        int s = ei[e];
        int d = ei[E + e];
        if ((unsigned)d < (unsigned)n) {
            int pos = atomicAdd(&fill[d], 1);
            if ((unsigned)s >= (unsigned)n) s = 0;
            colid[rowptr[d] + pos] = s;
        }
    }
}

// ---------------- concat helpers ----------------

__global__ void concat_kernel(const float4* __restrict__ f, const float4* __restrict__ c,
                              float4* __restrict__ A, int n) {
    int i = blockIdx.x * 256 + threadIdx.x;
    int total = n * 40;
    if (i < total) {
        int row = i / 40, j = i % 40;
        A[i] = (j < 32) ? f[row * 32 + j] : c[row * 8 + (j - 32)];
    }
}

__global__ void condcopy_kernel(const float4* __restrict__ c, float4* __restrict__ A, int n) {
    int i = blockIdx.x * 256 + threadIdx.x;
    if (i < n * 8) {
        int row = i / 8, j = i % 8;
        A[row * 24 + 16 + j] = c[row * 8 + j];
    }
}

// ---------------- GEMM: Y[n][OUT] = (X[n][K] @ W[K][OUT]) * dinv[row] ----------------

template <int OUT>
__global__ __launch_bounds__(256)
void gemm_kernel(const float* __restrict__ X, int ldx, int K,
                 const float* __restrict__ W,
                 const float* __restrict__ dinv,
                 float* __restrict__ Y, int n) {
    constexpr int TN = (OUT == 128) ? 8 : 4;
    __shared__ float As[32][64];
    __shared__ float Bs[32][OUT];
    const int t = threadIdx.x;
    const int tx = t & 15;
    const int ty = t >> 4;
    const int row0 = blockIdx.x * 64;

    float acc[4][TN];
#pragma unroll
    for (int r = 0; r < 4; r++)
#pragma unroll
        for (int c = 0; c < TN; c++) acc[r][c] = 0.f;

    const int ar = t >> 3;
    const int ak = (t & 7) << 2;

    for (int kt = 0; kt < K; kt += 32) {
#pragma unroll
        for (int i = 0; i < 2; i++) {
            int rr = ar + i * 32;
            int rg = row0 + rr;
            float4 v = make_float4(0.f, 0.f, 0.f, 0.f);
            if (rg < n) v = *(const float4*)(X + (size_t)rg * ldx + kt + ak);
            As[ak + 0][rr] = v.x; As[ak + 1][rr] = v.y;
            As[ak + 2][rr] = v.z; As[ak + 3][rr] = v.w;
        }
        constexpr int F4 = OUT / 4;
#pragma unroll
        for (int it = 0; it < (32 * F4) / 256; it++) {
            int idx = t + it * 256;
            int kr = idx / F4, c4 = (idx % F4) * 4;
            *(float4*)&Bs[kr][c4] = *(const float4*)(W + (size_t)(kt + kr) * OUT + c4);
        }
        __syncthreads();
#pragma unroll 4
        for (int k = 0; k < 32; k++) {
            const float4 a = *(const float4*)&As[k][ty << 2];
            const float4 b0 = *(const float4*)&Bs[k][tx << 2];
            float av[4] = {a.x, a.y, a.z, a.w};
            float bv[TN];
            bv[0] = b0.x; bv[1] = b0.y; bv[2] = b0.z; bv[3] = b0.w;
            if constexpr (OUT == 128) {
                const float4 b1 = *(const float4*)&Bs[k][64 + (tx << 2)];
                bv[4] = b1.x; bv[5] = b1.y; bv[6] = b1.z; bv[7] = b1.w;
            }
#pragma unroll
            for (int r = 0; r < 4; r++)
#pragma unroll
                for (int c = 0; c < TN; c++)
                    acc[r][c] = fmaf(av[r], bv[c], acc[r][c]);
        }
        __syncthreads();
    }
#pragma unroll
    for (int r = 0; r < 4; r++) {
        int rg = row0 + (ty << 2) + r;
        if (rg < n) {
            float di = dinv[rg];
            float4 o0 = make_float4(acc[r][0] * di, acc[r][1] * di,
                                    acc[r][2] * di, acc[r][3] * di);
            *(float4*)(Y + (size_t)rg * OUT + (tx << 2)) = o0;
            if constexpr (OUT == 128) {
                float4 o1 = make_float4(acc[r][4] * di, acc[r][5] * di,
                                        acc[r][6] * di, acc[r][7] * di);
                *(float4*)(Y + (size_t)rg * OUT + 64 + (tx << 2)) = o1;
            }
        }
    }
}

// ---------------- propagation ----------------

template <int OUT, bool TANH>
__global__ __launch_bounds__(256)
void prop_kernel(const float* __restrict__ hs, const float* __restrict__ dinv,
                 const int* __restrict__ rowptr, const int* __restrict__ colid,
                 const float* __restrict__ bias,
                 float* __restrict__ out, int ldo, int n) {
    int wave = threadIdx.x >> 6;
    int lane = threadIdx.x & 63;
    int node = blockIdx.x * 4 + wave;
    if (node >= n) return;
    int beg = rowptr[node], end = rowptr[node + 1];

    if constexpr (OUT == 128) {
        const float2* base = (const float2*)hs;
        float2 acc = base[(size_t)node * 64 + lane];
        int e = beg;
        for (; e + 4 <= end; e += 4) {
            int s0 = colid[e], s1 = colid[e + 1], s2 = colid[e + 2], s3 = colid[e + 3];
            float2 v0 = base[(size_t)s0 * 64 + lane];
            float2 v1 = base[(size_t)s1 * 64 + lane];
            float2 v2 = base[(size_t)s2 * 64 + lane];
            float2 v3 = base[(size_t)s3 * 64 + lane];
            acc.x += v0.x + v1.x; acc.y += v0.y + v1.y;
            acc.x += v2.x + v3.x; acc.y += v2.y + v3.y;
        }
        for (; e < end; e++) {
            int s = colid[e];
            float2 v = base[(size_t)s * 64 + lane];
            acc.x += v.x; acc.y += v.y;
        }
        float di = dinv[node];
        float ox = di * acc.x + bias[2 * lane];
        float oy = di * acc.y + bias[2 * lane + 1];
        if (TANH) { ox = tanhf(ox); oy = tanhf(oy); }
        *(float2*)(out + (size_t)node * ldo + 2 * lane) = make_float2(ox, oy);
    } else {
        float acc = hs[(size_t)node * 64 + lane];
        int e = beg;
        for (; e + 4 <= end; e += 4) {
            int s0 = colid[e], s1 = colid[e + 1], s2 = colid[e + 2], s3 = colid[e + 3];
            acc += hs[(size_t)s0 * 64 + lane] + hs[(size_t)s1 * 64 + lane] +
                   hs[(size_t)s2 * 64 + lane] + hs[(size_t)s3 * 64 + lane];
        }
        for (; e < end; e++) acc += hs[(size_t)colid[e] * 64 + lane];
        float v = dinv[node] * acc + bias[lane];
        if (TANH) v = tanhf(v);
        out[(size_t)node * ldo + lane] = v;
    }
}

// ---------------- launch ----------------

extern "C" void kernel_launch(void* const* d_in, const int* in_sizes, int n_in,
                              void* d_out, int out_size, void* d_ws, size_t ws_size,
                              hipStream_t stream) {
    const int n = NN, E = NE;
    const float* feature   = (const float*)d_in[0];
    const float* condition = (const float*)d_in[1];
    const int*   ei        = (const int*)d_in[2];
    const float* b_e1 = (const float*)d_in[4];
    const float* W_e1 = (const float*)d_in[3];
    const float* W_e2 = (const float*)d_in[5];  const float* b_e2 = (const float*)d_in[6];
    const float* W_e3 = (const float*)d_in[7];  const float* b_e3 = (const float*)d_in[8];
    const float* W_d1 = (const float*)d_in[9];  const float* b_d1 = (const float*)d_in[10];
    const float* W_d2 = (const float*)d_in[11]; const float* b_d2 = (const float*)d_in[12];
    const float* W_d3 = (const float*)d_in[13]; const float* b_d3 = (const float*)d_in[14];
    float* out = (float*)d_out;

    // workspace layout
    float* A    = (float*)d_ws;                 // n*160 floats
    float* B    = A + (size_t)n * 160;          // n*128 floats
    float* dinv = B + (size_t)n * 128;          // n floats
    int* cnt    = (int*)(dinv + n);             // n
    int* rowptr = cnt + n;                      // n+1
    int* fill   = rowptr + n + 1;               // n
    int* colid  = fill + n;                     // E
    int* bsum   = colid + E;                    // <=128+1

    hipMemsetAsync(cnt, 0, n * sizeof(int), stream);
    hipMemsetAsync(fill, 0, n * sizeof(int), stream);

    int eb = (E + 255) / 256;
    int nb = (n + 1023) / 1024;  // 98
    count_kernel<<<eb, 256, 0, stream>>>(ei, cnt, E, n);
    dinv_kernel<<<(n + 255) / 256, 256, 0, stream>>>(cnt, dinv, n);
    scan_blocksum<<<nb, 256, 0, stream>>>(cnt, bsum, n);
    scan_partials<<<1, 128, 0, stream>>>(bsum, rowptr, nb, n);
    scan_final<<<nb, 256, 0, stream>>>(cnt, bsum, rowptr, n);
    fill_kernel<<<eb, 256, 0, stream>>>(ei, rowptr, fill, colid, E, n);

    concat_kernel<<<(n * 40 + 255) / 256, 256, 0, stream>>>(
        (const float4*)feature, (const float4*)condition, (float4*)A, n);

    int gt = (n + 63) / 64;
    int pb = (n + 3) / 4;

    // encoder
    gemm_kernel<128><<<gt, 256, 0, stream>>>(A, 160, 160, W_e1, dinv, B, n);
    prop_kernel<128, true><<<pb, 256, 0, stream>>>(B, dinv, rowptr, colid, b_e1, A, 128, n);
    gemm_kernel<128><<<gt, 256, 0, stream>>>(A, 128, 128, W_e2, dinv, B, n);
    prop_kernel<128, true><<<pb, 256, 0, stream>>>(B, dinv, rowptr, colid, b_e2, A, 128, n);
    gemm_kernel<64><<<gt, 256, 0, stream>>>(A, 128, 128, W_e3, dinv, B, n);
    prop_kernel<64, false><<<pb, 256, 0, stream>>>(B, dinv, rowptr, colid, b_e3, A, 96, n);
    condcopy_kernel<<<(n * 8 + 255) / 256, 256, 0, stream>>>(
        (const float4*)condition, (float4*)A, n);

    // decoder
    gemm_kernel<128><<<gt, 256, 0, stream>>>(A, 96, 96, W_d1, dinv, B, n);
    prop_kernel<128, true><<<pb, 256, 0, stream>>>(B, dinv, rowptr, colid, b_d1, A, 128, n);
    gemm_kernel<128><<<gt, 256, 0, stream>>>(A, 128, 128, W_d2, dinv, B, n);
    prop_kernel<128, true><<<pb, 256, 0, stream>>>(B, dinv, rowptr, colid, b_d2, A, 128, n);
    gemm_kernel<128><<<gt, 256, 0, stream>>>(A, 128, 128, W_d3, dinv, B, n);
    prop_kernel<128, false><<<pb, 256, 0, stream>>>(B, dinv, rowptr, colid, b_d3, out, 128, n);
}

// Round 3
// 1243.682 us; speedup vs baseline: 1.1398x; 1.0087x over previous
//
#include <hip/hip_runtime.h>
#include <math.h>

#define NN 100000
#define NE 1600000

// ---------------- CSR build ----------------

__global__ void count_kernel(const int* __restrict__ ei, int* __restrict__ cnt,
                             int E, int n) {
    int e = blockIdx.x * 256 + threadIdx.x;
    if (e < E) {
        int d = ei[E + e];
        if ((unsigned)d < (unsigned)n) atomicAdd(&cnt[d], 1);
    }
}

__global__ void dinv_kernel(const int* __restrict__ cnt, float* __restrict__ dinv, int n) {
    int i = blockIdx.x * 256 + threadIdx.x;
    if (i < n) dinv[i] = 1.0f / sqrtf((float)cnt[i] + 1.0f);
}

// ---- hierarchical exclusive scan: cnt[0..n) -> rowptr[0..n] ----
__global__ __launch_bounds__(256)
void scan_blocksum(const int* __restrict__ cnt, int* __restrict__ bsum, int n) {
    __shared__ int red[256];
    int t = threadIdx.x;
    int base = blockIdx.x * 1024 + t * 4;
    int s = 0;
    if (base + 3 < n) {
        int4 v = *(const int4*)(cnt + base);
        s = v.x + v.y + v.z + v.w;
    } else {
        for (int j = 0; j < 4; j++) if (base + j < n) s += cnt[base + j];
    }
    red[t] = s;
    __syncthreads();
    for (int off = 128; off > 0; off >>= 1) {
        if (t < off) red[t] += red[t + off];
        __syncthreads();
    }
    if (t == 0) bsum[blockIdx.x] = red[0];
}

__global__ void scan_partials(int* __restrict__ bsum, int* __restrict__ rowptr,
                              int nb, int n) {
    __shared__ int sh[128];
    int t = threadIdx.x;
    int v = (t < nb) ? bsum[t] : 0;
    sh[t] = v;
    __syncthreads();
    for (int off = 1; off < 128; off <<= 1) {
        int u = (t >= off) ? sh[t - off] : 0;
        __syncthreads();
        sh[t] += u;
        __syncthreads();
    }
    if (t < nb) bsum[t] = (t == 0) ? 0 : sh[t - 1];
    if (t == 0) rowptr[n] = sh[nb - 1];
}

__global__ __launch_bounds__(256)
void scan_final(const int* __restrict__ cnt, const int* __restrict__ bsum,
                int* __restrict__ rowptr, int n) {
    __shared__ int sh[256];
    int t = threadIdx.x;
    int base = blockIdx.x * 1024 + t * 4;
    int v0 = 0, v1 = 0, v2 = 0, v3 = 0;
    if (base + 3 < n) {
        int4 v = *(const int4*)(cnt + base);
        v0 = v.x; v1 = v.y; v2 = v.z; v3 = v.w;
    } else {
        if (base < n)     v0 = cnt[base];
        if (base + 1 < n) v1 = cnt[base + 1];
        if (base + 2 < n) v2 = cnt[base + 2];
        if (base + 3 < n) v3 = cnt[base + 3];
    }
    sh[t] = v0 + v1 + v2 + v3;
    __syncthreads();
    for (int off = 1; off < 256; off <<= 1) {
        int u = (t >= off) ? sh[t - off] : 0;
        __syncthreads();
        sh[t] += u;
        __syncthreads();
    }
    int o = bsum[blockIdx.x] + ((t == 0) ? 0 : sh[t - 1]);
    if (base < n)     rowptr[base]     = o;
    if (base + 1 < n) rowptr[base + 1] = o + v0;
    if (base + 2 < n) rowptr[base + 2] = o + v0 + v1;
    if (base + 3 < n) rowptr[base + 3] = o + v0 + v1 + v2;
}

__global__ void fill_kernel(const int* __restrict__ ei, const int* __restrict__ rowptr,
                            int* __restrict__ fill, int* __restrict__ colid, int E, int n) {
    int e = blockIdx.x * 256 + threadIdx.x;
    if (e < E) {
        int s = ei[e];
        int d = ei[E + e];
        if ((unsigned)d < (unsigned)n) {
            int pos = atomicAdd(&fill[d], 1);
            if ((unsigned)s >= (unsigned)n) s = 0;
            colid[rowptr[d] + pos] = s;
        }
    }
}

// ---------------- concat helpers ----------------

__global__ void concat_kernel(const float4* __restrict__ f, const float4* __restrict__ c,
                              float4* __restrict__ A, int n) {
    int i = blockIdx.x * 256 + threadIdx.x;
    int total = n * 40;
    if (i < total) {
        int row = i / 40, j = i % 40;
        A[i] = (j < 32) ? f[row * 32 + j] : c[row * 8 + (j - 32)];
    }
}

__global__ void condcopy_kernel(const float4* __restrict__ c, float4* __restrict__ A, int n) {
    int i = blockIdx.x * 256 + threadIdx.x;
    if (i < n * 8) {
        int row = i / 8, j = i % 8;
        A[row * 24 + 16 + j] = c[row * 8 + j];
    }
}

// ---------------- GEMM: Y[n][OUT] = (X[n][K] @ W[K][OUT]) * dinv[row] ----------------

template <int OUT>
__global__ __launch_bounds__(256)
void gemm_kernel(const float* __restrict__ X, int ldx, int K,
                 const float* __restrict__ W,
                 const float* __restrict__ dinv,
                 float* __restrict__ Y, int n) {
    constexpr int TN = (OUT == 128) ? 8 : 4;
    __shared__ float As[32][64];
    __shared__ float Bs[32][OUT];
    const int t = threadIdx.x;
    const int tx = t & 15;
    const int ty = t >> 4;
    const int row0 = blockIdx.x * 64;

    float acc[4][TN];
#pragma unroll
    for (int r = 0; r < 4; r++)
#pragma unroll
        for (int c = 0; c < TN; c++) acc[r][c] = 0.f;

    const int ar = t >> 3;
    const int ak = (t & 7) << 2;

    for (int kt = 0; kt < K; kt += 32) {
#pragma unroll
        for (int i = 0; i < 2; i++) {
            int rr = ar + i * 32;
            int rg = row0 + rr;
            float4 v = make_float4(0.f, 0.f, 0.f, 0.f);
            if (rg < n) v = *(const float4*)(X + (size_t)rg * ldx + kt + ak);
            As[ak + 0][rr] = v.x; As[ak + 1][rr] = v.y;
            As[ak + 2][rr] = v.z; As[ak + 3][rr] = v.w;
        }
        constexpr int F4 = OUT / 4;
#pragma unroll
        for (int it = 0; it < (32 * F4) / 256; it++) {
            int idx = t + it * 256;
            int kr = idx / F4, c4 = (idx % F4) * 4;
            *(float4*)&Bs[kr][c4] = *(const float4*)(W + (size_t)(kt + kr) * OUT + c4);
        }
        __syncthreads();
#pragma unroll 4
        for (int k = 0; k < 32; k++) {
            const float4 a = *(const float4*)&As[k][ty << 2];
            const float4 b0 = *(const float4*)&Bs[k][tx << 2];
            float av[4] = {a.x, a.y, a.z, a.w};
            float bv[TN];
            bv[0] = b0.x; bv[1] = b0.y; bv[2] = b0.z; bv[3] = b0.w;
            if constexpr (OUT == 128) {
                const float4 b1 = *(const float4*)&Bs[k][64 + (tx << 2)];
                bv[4] = b1.x; bv[5] = b1.y; bv[6] = b1.z; bv[7] = b1.w;
            }
#pragma unroll
            for (int r = 0; r < 4; r++)
#pragma unroll
                for (int c = 0; c < TN; c++)
                    acc[r][c] = fmaf(av[r], bv[c], acc[r][c]);
        }
        __syncthreads();
    }
#pragma unroll
    for (int r = 0; r < 4; r++) {
        int rg = row0 + (ty << 2) + r;
        if (rg < n) {
            float di = dinv[rg];
            float4 o0 = make_float4(acc[r][0] * di, acc[r][1] * di,
                                    acc[r][2] * di, acc[r][3] * di);
            *(float4*)(Y + (size_t)rg * OUT + (tx << 2)) = o0;
            if constexpr (OUT == 128) {
                float4 o1 = make_float4(acc[r][4] * di, acc[r][5] * di,
                                        acc[r][6] * di, acc[r][7] * di);
                *(float4*)(Y + (size_t)rg * OUT + 64 + (tx << 2)) = o1;
            }
        }
    }
}

// ---------------- propagation ----------------
// unroll 8: keep 8 gathers outstanding per wave to cover L3/HBM latency

template <int OUT, bool TANH>
__global__ __launch_bounds__(256)
void prop_kernel(const float* __restrict__ hs, const float* __restrict__ dinv,
                 const int* __restrict__ rowptr, const int* __restrict__ colid,
                 const float* __restrict__ bias,
                 float* __restrict__ out, int ldo, int n) {
    int wave = threadIdx.x >> 6;
    int lane = threadIdx.x & 63;
    int node = blockIdx.x * 4 + wave;
    if (node >= n) return;
    int beg = rowptr[node], end = rowptr[node + 1];

    if constexpr (OUT == 128) {
        const float2* base = (const float2*)hs;
        float2 acc = base[(size_t)node * 64 + lane];
        float2 acc2 = make_float2(0.f, 0.f);
        int e = beg;
        for (; e + 8 <= end; e += 8) {
            int s[8];
#pragma unroll
            for (int j = 0; j < 8; j++) s[j] = colid[e + j];
            float2 v[8];
#pragma unroll
            for (int j = 0; j < 8; j++) v[j] = base[(size_t)s[j] * 64 + lane];
#pragma unroll
            for (int j = 0; j < 8; j += 2) {
                acc.x += v[j].x;     acc.y += v[j].y;
                acc2.x += v[j + 1].x; acc2.y += v[j + 1].y;
            }
        }
        if (e + 4 <= end) {
            int s[4];
#pragma unroll
            for (int j = 0; j < 4; j++) s[j] = colid[e + j];
            float2 v[4];
#pragma unroll
            for (int j = 0; j < 4; j++) v[j] = base[(size_t)s[j] * 64 + lane];
            acc.x += v[0].x + v[2].x; acc.y += v[0].y + v[2].y;
            acc2.x += v[1].x + v[3].x; acc2.y += v[1].y + v[3].y;
            e += 4;
        }
        for (; e < end; e++) {
            int s = colid[e];
            float2 v = base[(size_t)s * 64 + lane];
            acc.x += v.x; acc.y += v.y;
        }
        acc.x += acc2.x; acc.y += acc2.y;
        float di = dinv[node];
        float ox = di * acc.x + bias[2 * lane];
        float oy = di * acc.y + bias[2 * lane + 1];
        if (TANH) { ox = tanhf(ox); oy = tanhf(oy); }
        *(float2*)(out + (size_t)node * ldo + 2 * lane) = make_float2(ox, oy);
    } else {
        float acc = hs[(size_t)node * 64 + lane];
        float acc2 = 0.f;
        int e = beg;
        for (; e + 8 <= end; e += 8) {
            int s[8];
#pragma unroll
            for (int j = 0; j < 8; j++) s[j] = colid[e + j];
            float v[8];
#pragma unroll
            for (int j = 0; j < 8; j++) v[j] = hs[(size_t)s[j] * 64 + lane];
#pragma unroll
            for (int j = 0; j < 8; j += 2) { acc += v[j]; acc2 += v[j + 1]; }
        }
        if (e + 4 <= end) {
            int s[4];
#pragma unroll
            for (int j = 0; j < 4; j++) s[j] = colid[e + j];
            float v[4];
#pragma unroll
            for (int j = 0; j < 4; j++) v[j] = hs[(size_t)s[j] * 64 + lane];
            acc += v[0] + v[2]; acc2 += v[1] + v[3];
            e += 4;
        }
        for (; e < end; e++) acc += hs[(size_t)colid[e] * 64 + lane];
        acc += acc2;
        float v = dinv[node] * acc + bias[lane];
        if (TANH) v = tanhf(v);
        out[(size_t)node * ldo + lane] = v;
    }
}

// ---------------- launch ----------------

extern "C" void kernel_launch(void* const* d_in, const int* in_sizes, int n_in,
                              void* d_out, int out_size, void* d_ws, size_t ws_size,
                              hipStream_t stream) {
    const int n = NN, E = NE;
    const float* feature   = (const float*)d_in[0];
    const float* condition = (const float*)d_in[1];
    const int*   ei        = (const int*)d_in[2];
    const float* W_e1 = (const float*)d_in[3];  const float* b_e1 = (const float*)d_in[4];
    const float* W_e2 = (const float*)d_in[5];  const float* b_e2 = (const float*)d_in[6];
    const float* W_e3 = (const float*)d_in[7];  const float* b_e3 = (const float*)d_in[8];
    const float* W_d1 = (const float*)d_in[9];  const float* b_d1 = (const float*)d_in[10];
    const float* W_d2 = (const float*)d_in[11]; const float* b_d2 = (const float*)d_in[12];
    const float* W_d3 = (const float*)d_in[13]; const float* b_d3 = (const float*)d_in[14];
    float* out = (float*)d_out;

    float* A    = (float*)d_ws;                 // n*160 floats
    float* B    = A + (size_t)n * 160;          // n*128 floats
    float* dinv = B + (size_t)n * 128;          // n floats
    int* cnt    = (int*)(dinv + n);             // n
    int* rowptr = cnt + n;                      // n+1
    int* fill   = rowptr + n + 1;               // n
    int* colid  = fill + n;                     // E
    int* bsum   = colid + E;                    // <=128

    hipMemsetAsync(cnt, 0, n * sizeof(int), stream);
    hipMemsetAsync(fill, 0, n * sizeof(int), stream);

    int eb = (E + 255) / 256;
    int nb = (n + 1023) / 1024;
    count_kernel<<<eb, 256, 0, stream>>>(ei, cnt, E, n);
    dinv_kernel<<<(n + 255) / 256, 256, 0, stream>>>(cnt, dinv, n);
    scan_blocksum<<<nb, 256, 0, stream>>>(cnt, bsum, n);
    scan_partials<<<1, 128, 0, stream>>>(bsum, rowptr, nb, n);
    scan_final<<<nb, 256, 0, stream>>>(cnt, bsum, rowptr, n);
    fill_kernel<<<eb, 256, 0, stream>>>(ei, rowptr, fill, colid, E, n);

    concat_kernel<<<(n * 40 + 255) / 256, 256, 0, stream>>>(
        (const float4*)feature, (const float4*)condition, (float4*)A, n);

    int gt = (n + 63) / 64;
    int pb = (n + 3) / 4;

    // encoder
    gemm_kernel<128><<<gt, 256, 0, stream>>>(A, 160, 160, W_e1, dinv, B, n);
    prop_kernel<128, true><<<pb, 256, 0, stream>>>(B, dinv, rowptr, colid, b_e1, A, 128, n);
    gemm_kernel<128><<<gt, 256, 0, stream>>>(A, 128, 128, W_e2, dinv, B, n);
    prop_kernel<128, true><<<pb, 256, 0, stream>>>(B, dinv, rowptr, colid, b_e2, A, 128, n);
    gemm_kernel<64><<<gt, 256, 0, stream>>>(A, 128, 128, W_e3, dinv, B, n);
    prop_kernel<64, false><<<pb, 256, 0, stream>>>(B, dinv, rowptr, colid, b_e3, A, 96, n);
    condcopy_kernel<<<(n * 8 + 255) / 256, 256, 0, stream>>>(
        (const float4*)condition, (float4*)A, n);

    // decoder
    gemm_kernel<128><<<gt, 256, 0, stream>>>(A, 96, 96, W_d1, dinv, B, n);
    prop_kernel<128, true><<<pb, 256, 0, stream>>>(B, dinv, rowptr, colid, b_d1, A, 128, n);
    gemm_kernel<128><<<gt, 256, 0, stream>>>(A, 128, 128, W_d2, dinv, B, n);
    prop_kernel<128, true><<<pb, 256, 0, stream>>>(B, dinv, rowptr, colid, b_d2, A, 128, n);
    gemm_kernel<128><<<gt, 256, 0, stream>>>(A, 128, 128, W_d3, dinv, B, n);
    prop_kernel<128, false><<<pb, 256, 0, stream>>>(B, dinv, rowptr, colid, b_d3, out, 128, n);
}

// Round 4
// 964.349 us; speedup vs baseline: 1.4700x; 1.2897x over previous
//
#include <hip/hip_runtime.h>
#include <hip/hip_fp16.h>
#include <math.h>

#define NN 100000
#define NE 1600000

// ---------------- CSR build ----------------

__global__ void count_kernel(const int* __restrict__ ei, int* __restrict__ cnt,
                             int E, int n) {
    int e = blockIdx.x * 256 + threadIdx.x;
    if (e < E) {
        int d = ei[E + e];
        if ((unsigned)d < (unsigned)n) atomicAdd(&cnt[d], 1);
    }
}

__global__ void dinv_kernel(const int* __restrict__ cnt, float* __restrict__ dinv, int n) {
    int i = blockIdx.x * 256 + threadIdx.x;
    if (i < n) dinv[i] = 1.0f / sqrtf((float)cnt[i] + 1.0f);
}

// ---- hierarchical exclusive scan: cnt[0..n) -> rowptr[0..n] ----
__global__ __launch_bounds__(256)
void scan_blocksum(const int* __restrict__ cnt, int* __restrict__ bsum, int n) {
    __shared__ int red[256];
    int t = threadIdx.x;
    int base = blockIdx.x * 1024 + t * 4;
    int s = 0;
    if (base + 3 < n) {
        int4 v = *(const int4*)(cnt + base);
        s = v.x + v.y + v.z + v.w;
    } else {
        for (int j = 0; j < 4; j++) if (base + j < n) s += cnt[base + j];
    }
    red[t] = s;
    __syncthreads();
    for (int off = 128; off > 0; off >>= 1) {
        if (t < off) red[t] += red[t + off];
        __syncthreads();
    }
    if (t == 0) bsum[blockIdx.x] = red[0];
}

__global__ void scan_partials(int* __restrict__ bsum, int* __restrict__ rowptr,
                              int nb, int n) {
    __shared__ int sh[128];
    int t = threadIdx.x;
    int v = (t < nb) ? bsum[t] : 0;
    sh[t] = v;
    __syncthreads();
    for (int off = 1; off < 128; off <<= 1) {
        int u = (t >= off) ? sh[t - off] : 0;
        __syncthreads();
        sh[t] += u;
        __syncthreads();
    }
    if (t < nb) bsum[t] = (t == 0) ? 0 : sh[t - 1];
    if (t == 0) rowptr[n] = sh[nb - 1];
}

__global__ __launch_bounds__(256)
void scan_final(const int* __restrict__ cnt, const int* __restrict__ bsum,
                int* __restrict__ rowptr, int n) {
    __shared__ int sh[256];
    int t = threadIdx.x;
    int base = blockIdx.x * 1024 + t * 4;
    int v0 = 0, v1 = 0, v2 = 0, v3 = 0;
    if (base + 3 < n) {
        int4 v = *(const int4*)(cnt + base);
        v0 = v.x; v1 = v.y; v2 = v.z; v3 = v.w;
    } else {
        if (base < n)     v0 = cnt[base];
        if (base + 1 < n) v1 = cnt[base + 1];
        if (base + 2 < n) v2 = cnt[base + 2];
        if (base + 3 < n) v3 = cnt[base + 3];
    }
    sh[t] = v0 + v1 + v2 + v3;
    __syncthreads();
    for (int off = 1; off < 256; off <<= 1) {
        int u = (t >= off) ? sh[t - off] : 0;
        __syncthreads();
        sh[t] += u;
        __syncthreads();
    }
    int o = bsum[blockIdx.x] + ((t == 0) ? 0 : sh[t - 1]);
    if (base < n)     rowptr[base]     = o;
    if (base + 1 < n) rowptr[base + 1] = o + v0;
    if (base + 2 < n) rowptr[base + 2] = o + v0 + v1;
    if (base + 3 < n) rowptr[base + 3] = o + v0 + v1 + v2;
}

__global__ void fill_kernel(const int* __restrict__ ei, const int* __restrict__ rowptr,
                            int* __restrict__ fill, int* __restrict__ colid, int E, int n) {
    int e = blockIdx.x * 256 + threadIdx.x;
    if (e < E) {
        int s = ei[e];
        int d = ei[E + e];
        if ((unsigned)d < (unsigned)n) {
            int pos = atomicAdd(&fill[d], 1);
            if ((unsigned)s >= (unsigned)n) s = 0;
            colid[rowptr[d] + pos] = s;
        }
    }
}

// ---------------- concat helpers ----------------

__global__ void concat_kernel(const float4* __restrict__ f, const float4* __restrict__ c,
                              float4* __restrict__ A, int n) {
    int i = blockIdx.x * 256 + threadIdx.x;
    int total = n * 40;
    if (i < total) {
        int row = i / 40, j = i % 40;
        A[i] = (j < 32) ? f[row * 32 + j] : c[row * 8 + (j - 32)];
    }
}

__global__ void condcopy_kernel(const float4* __restrict__ c, float4* __restrict__ A, int n) {
    int i = blockIdx.x * 256 + threadIdx.x;
    if (i < n * 8) {
        int row = i / 8, j = i % 8;
        A[row * 24 + 16 + j] = c[row * 8 + j];
    }
}

// ---------------- GEMM: Y16[n][OUT] = fp16( (X[n][K] @ W[K][OUT]) * dinv[row] ) ----------------

template <int OUT>
__global__ __launch_bounds__(256)
void gemm_kernel(const float* __restrict__ X, int ldx, int K,
                 const float* __restrict__ W,
                 const float* __restrict__ dinv,
                 __half* __restrict__ Y, int n) {
    constexpr int TN = (OUT == 128) ? 8 : 4;
    __shared__ float As[32][64];
    __shared__ float Bs[32][OUT];
    const int t = threadIdx.x;
    const int tx = t & 15;
    const int ty = t >> 4;
    const int row0 = blockIdx.x * 64;

    float acc[4][TN];
#pragma unroll
    for (int r = 0; r < 4; r++)
#pragma unroll
        for (int c = 0; c < TN; c++) acc[r][c] = 0.f;

    const int ar = t >> 3;
    const int ak = (t & 7) << 2;

    for (int kt = 0; kt < K; kt += 32) {
#pragma unroll
        for (int i = 0; i < 2; i++) {
            int rr = ar + i * 32;
            int rg = row0 + rr;
            float4 v = make_float4(0.f, 0.f, 0.f, 0.f);
            if (rg < n) v = *(const float4*)(X + (size_t)rg * ldx + kt + ak);
            As[ak + 0][rr] = v.x; As[ak + 1][rr] = v.y;
            As[ak + 2][rr] = v.z; As[ak + 3][rr] = v.w;
        }
        constexpr int F4 = OUT / 4;
#pragma unroll
        for (int it = 0; it < (32 * F4) / 256; it++) {
            int idx = t + it * 256;
            int kr = idx / F4, c4 = (idx % F4) * 4;
            *(float4*)&Bs[kr][c4] = *(const float4*)(W + (size_t)(kt + kr) * OUT + c4);
        }
        __syncthreads();
#pragma unroll 4
        for (int k = 0; k < 32; k++) {
            const float4 a = *(const float4*)&As[k][ty << 2];
            const float4 b0 = *(const float4*)&Bs[k][tx << 2];
            float av[4] = {a.x, a.y, a.z, a.w};
            float bv[TN];
            bv[0] = b0.x; bv[1] = b0.y; bv[2] = b0.z; bv[3] = b0.w;
            if constexpr (OUT == 128) {
                const float4 b1 = *(const float4*)&Bs[k][64 + (tx << 2)];
                bv[4] = b1.x; bv[5] = b1.y; bv[6] = b1.z; bv[7] = b1.w;
            }
#pragma unroll
            for (int r = 0; r < 4; r++)
#pragma unroll
                for (int c = 0; c < TN; c++)
                    acc[r][c] = fmaf(av[r], bv[c], acc[r][c]);
        }
        __syncthreads();
    }
#pragma unroll
    for (int r = 0; r < 4; r++) {
        int rg = row0 + (ty << 2) + r;
        if (rg < n) {
            float di = dinv[rg];
            union { __half2 h2[2]; float2 f2; } u0;
            u0.h2[0] = __floats2half2_rn(acc[r][0] * di, acc[r][1] * di);
            u0.h2[1] = __floats2half2_rn(acc[r][2] * di, acc[r][3] * di);
            *(float2*)(Y + (size_t)rg * OUT + (tx << 2)) = u0.f2;
            if constexpr (OUT == 128) {
                union { __half2 h2[2]; float2 f2; } u1;
                u1.h2[0] = __floats2half2_rn(acc[r][4] * di, acc[r][5] * di);
                u1.h2[1] = __floats2half2_rn(acc[r][6] * di, acc[r][7] * di);
                *(float2*)(Y + (size_t)rg * OUT + 64 + (tx << 2)) = u1.f2;
            }
        }
    }
}

// ---------------- propagation (fp16 gather, fp32 accumulate) ----------------

template <int OUT, bool TANH>
__global__ __launch_bounds__(256)
void prop_kernel(const __half* __restrict__ hs, const float* __restrict__ dinv,
                 const int* __restrict__ rowptr, const int* __restrict__ colid,
                 const float* __restrict__ bias,
                 float* __restrict__ out, int ldo, int n) {
    int wave = threadIdx.x >> 6;
    int lane = threadIdx.x & 63;
    int node = blockIdx.x * 4 + wave;
    if (node >= n) return;
    int beg = rowptr[node], end = rowptr[node + 1];

    if constexpr (OUT == 128) {
        const __half2* base = (const __half2*)hs;
        float2 self = __half22float2(base[(size_t)node * 64 + lane]);
        float accx = self.x, accy = self.y;
        float accx2 = 0.f, accy2 = 0.f;
        int e = beg;
        for (; e + 8 <= end; e += 8) {
            int s[8];
#pragma unroll
            for (int j = 0; j < 8; j++) s[j] = colid[e + j];
            __half2 v[8];
#pragma unroll
            for (int j = 0; j < 8; j++) v[j] = base[(size_t)s[j] * 64 + lane];
#pragma unroll
            for (int j = 0; j < 8; j += 2) {
                float2 f0 = __half22float2(v[j]);
                float2 f1 = __half22float2(v[j + 1]);
                accx += f0.x; accy += f0.y;
                accx2 += f1.x; accy2 += f1.y;
            }
        }
        if (e + 4 <= end) {
            int s[4];
#pragma unroll
            for (int j = 0; j < 4; j++) s[j] = colid[e + j];
            __half2 v[4];
#pragma unroll
            for (int j = 0; j < 4; j++) v[j] = base[(size_t)s[j] * 64 + lane];
            float2 f0 = __half22float2(v[0]), f1 = __half22float2(v[1]);
            float2 f2 = __half22float2(v[2]), f3 = __half22float2(v[3]);
            accx += f0.x + f2.x; accy += f0.y + f2.y;
            accx2 += f1.x + f3.x; accy2 += f1.y + f3.y;
            e += 4;
        }
        for (; e < end; e++) {
            float2 f = __half22float2(base[(size_t)colid[e] * 64 + lane]);
            accx += f.x; accy += f.y;
        }
        accx += accx2; accy += accy2;
        float di = dinv[node];
        float ox = di * accx + bias[2 * lane];
        float oy = di * accy + bias[2 * lane + 1];
        if (TANH) { ox = tanhf(ox); oy = tanhf(oy); }
        *(float2*)(out + (size_t)node * ldo + 2 * lane) = make_float2(ox, oy);
    } else {
        float acc = __half2float(hs[(size_t)node * 64 + lane]);
        float acc2 = 0.f;
        int e = beg;
        for (; e + 8 <= end; e += 8) {
            int s[8];
#pragma unroll
            for (int j = 0; j < 8; j++) s[j] = colid[e + j];
            __half v[8];
#pragma unroll
            for (int j = 0; j < 8; j++) v[j] = hs[(size_t)s[j] * 64 + lane];
#pragma unroll
            for (int j = 0; j < 8; j += 2) {
                acc += __half2float(v[j]);
                acc2 += __half2float(v[j + 1]);
            }
        }
        if (e + 4 <= end) {
            int s[4];
#pragma unroll
            for (int j = 0; j < 4; j++) s[j] = colid[e + j];
            __half v[4];
#pragma unroll
            for (int j = 0; j < 4; j++) v[j] = hs[(size_t)s[j] * 64 + lane];
            acc += __half2float(v[0]) + __half2float(v[2]);
            acc2 += __half2float(v[1]) + __half2float(v[3]);
            e += 4;
        }
        for (; e < end; e++) acc += __half2float(hs[(size_t)colid[e] * 64 + lane]);
        acc += acc2;
        float v = dinv[node] * acc + bias[lane];
        if (TANH) v = tanhf(v);
        out[(size_t)node * ldo + lane] = v;
    }
}

// ---------------- launch ----------------

extern "C" void kernel_launch(void* const* d_in, const int* in_sizes, int n_in,
                              void* d_out, int out_size, void* d_ws, size_t ws_size,
                              hipStream_t stream) {
    const int n = NN, E = NE;
    const float* feature   = (const float*)d_in[0];
    const float* condition = (const float*)d_in[1];
    const int*   ei        = (const int*)d_in[2];
    const float* W_e1 = (const float*)d_in[3];  const float* b_e1 = (const float*)d_in[4];
    const float* W_e2 = (const float*)d_in[5];  const float* b_e2 = (const float*)d_in[6];
    const float* W_e3 = (const float*)d_in[7];  const float* b_e3 = (const float*)d_in[8];
    const float* W_d1 = (const float*)d_in[9];  const float* b_d1 = (const float*)d_in[10];
    const float* W_d2 = (const float*)d_in[11]; const float* b_d2 = (const float*)d_in[12];
    const float* W_d3 = (const float*)d_in[13]; const float* b_d3 = (const float*)d_in[14];
    float* out = (float*)d_out;

    float*  A    = (float*)d_ws;                 // n*160 floats
    __half* H16  = (__half*)(A + (size_t)n * 160); // n*128 halves (25.6 MB)
    float*  dinv = (float*)(H16 + (size_t)n * 128);
    int* cnt    = (int*)(dinv + n);              // n
    int* rowptr = cnt + n;                       // n+1
    int* fill   = rowptr + n + 1;                // n
    int* colid  = fill + n;                      // E
    int* bsum   = colid + E;                     // <=128

    hipMemsetAsync(cnt, 0, n * sizeof(int), stream);
    hipMemsetAsync(fill, 0, n * sizeof(int), stream);

    int eb = (E + 255) / 256;
    int nb = (n + 1023) / 1024;
    count_kernel<<<eb, 256, 0, stream>>>(ei, cnt, E, n);
    dinv_kernel<<<(n + 255) / 256, 256, 0, stream>>>(cnt, dinv, n);
    scan_blocksum<<<nb, 256, 0, stream>>>(cnt, bsum, n);
    scan_partials<<<1, 128, 0, stream>>>(bsum, rowptr, nb, n);
    scan_final<<<nb, 256, 0, stream>>>(cnt, bsum, rowptr, n);
    fill_kernel<<<eb, 256, 0, stream>>>(ei, rowptr, fill, colid, E, n);

    concat_kernel<<<(n * 40 + 255) / 256, 256, 0, stream>>>(
        (const float4*)feature, (const float4*)condition, (float4*)A, n);

    int gt = (n + 63) / 64;
    int pb = (n + 3) / 4;

    // encoder
    gemm_kernel<128><<<gt, 256, 0, stream>>>(A, 160, 160, W_e1, dinv, H16, n);
    prop_kernel<128, true><<<pb, 256, 0, stream>>>(H16, dinv, rowptr, colid, b_e1, A, 128, n);
    gemm_kernel<128><<<gt, 256, 0, stream>>>(A, 128, 128, W_e2, dinv, H16, n);
    prop_kernel<128, true><<<pb, 256, 0, stream>>>(H16, dinv, rowptr, colid, b_e2, A, 128, n);
    gemm_kernel<64><<<gt, 256, 0, stream>>>(A, 128, 128, W_e3, dinv, H16, n);
    prop_kernel<64, false><<<pb, 256, 0, stream>>>(H16, dinv, rowptr, colid, b_e3, A, 96, n);
    condcopy_kernel<<<(n * 8 + 255) / 256, 256, 0, stream>>>(
        (const float4*)condition, (float4*)A, n);

    // decoder
    gemm_kernel<128><<<gt, 256, 0, stream>>>(A, 96, 96, W_d1, dinv, H16, n);
    prop_kernel<128, true><<<pb, 256, 0, stream>>>(H16, dinv, rowptr, colid, b_d1, A, 128, n);
    gemm_kernel<128><<<gt, 256, 0, stream>>>(A, 128, 128, W_d2, dinv, H16, n);
    prop_kernel<128, true><<<pb, 256, 0, stream>>>(H16, dinv, rowptr, colid, b_d2, A, 128, n);
    gemm_kernel<128><<<gt, 256, 0, stream>>>(A, 128, 128, W_d3, dinv, H16, n);
    prop_kernel<128, false><<<pb, 256, 0, stream>>>(H16, dinv, rowptr, colid, b_d3, out, 128, n);
}

// Round 5
// 881.384 us; speedup vs baseline: 1.6084x; 1.0941x over previous
//
#include <hip/hip_runtime.h>
#include <hip/hip_fp16.h>
#include <math.h>

#define NN 100000
#define NE 1600000
#define NB ((NN + 255) >> 8)   // 391 buckets of 256 nodes
#define CHUNK 8192
#define CAP 8192               // max edges per bucket (avg 4096, +60 sigma margin)

// ---------------- bucketed CSR build ----------------

// pass 1: coarse histogram by dst>>8 (LDS-aggregated)
__global__ __launch_bounds__(256)
void coarse_hist(const int* __restrict__ ei, int* __restrict__ bucket_cnt, int E) {
    __shared__ int h[512];
    int t = threadIdx.x;
    for (int i = t; i < 512; i += 256) h[i] = 0;
    __syncthreads();
    int base = blockIdx.x * CHUNK;
    int lim = min(base + CHUNK, E);
    for (int e = base + t; e < lim; e += 256) {
        int d = ei[E + e];
        atomicAdd(&h[d >> 8], 1);
    }
    __syncthreads();
    for (int i = t; i < 512; i += 256)
        if (h[i]) atomicAdd(&bucket_cnt[i], h[i]);
}

// pass 2: scan 391 bucket counts (1 block); init fill cursors
__global__ void scan_buckets(const int* __restrict__ bucket_cnt,
                             int* __restrict__ bucket_base,
                             int* __restrict__ bucket_fill) {
    __shared__ int sh[512];
    int t = threadIdx.x;  // 512 threads
    int v = (t < NB) ? bucket_cnt[t] : 0;
    sh[t] = v;
    __syncthreads();
    for (int off = 1; off < 512; off <<= 1) {
        int u = (t >= off) ? sh[t - off] : 0;
        __syncthreads();
        sh[t] += u;
        __syncthreads();
    }
    int ex = (t == 0) ? 0 : sh[t - 1];
    if (t <= NB) bucket_base[t] = ex;
    if (t < NB) bucket_fill[t] = ex;
}

// pass 3: scatter packed (dst,src) pairs into bucket regions, block-reserved chunks
__global__ __launch_bounds__(256)
void coarse_scatter(const int* __restrict__ ei, int* __restrict__ bucket_fill,
                    unsigned long long* __restrict__ pairs, int E) {
    __shared__ int h[512];
    __shared__ int base[512];
    int t = threadIdx.x;
    for (int i = t; i < 512; i += 256) h[i] = 0;
    __syncthreads();
    int cbase = blockIdx.x * CHUNK;
    int lim = min(cbase + CHUNK, E);
    for (int e = cbase + t; e < lim; e += 256) {
        int d = ei[E + e];
        atomicAdd(&h[d >> 8], 1);
    }
    __syncthreads();
    for (int i = t; i < 512; i += 256)
        base[i] = h[i] ? atomicAdd(&bucket_fill[i], h[i]) : 0;
    __syncthreads();
    for (int i = t; i < 512; i += 256) h[i] = 0;
    __syncthreads();
    for (int e = cbase + t; e < lim; e += 256) {
        int s = ei[e];
        int d = ei[E + e];
        int b = d >> 8;
        int r = atomicAdd(&h[b], 1);
        pairs[base[b] + r] =
            ((unsigned long long)(unsigned)d << 32) | (unsigned)s;
    }
}

// pass 4: per-bucket fine CSR: rowptr + dinv + coalesced colid
__global__ __launch_bounds__(256)
void fine_csr(const unsigned long long* __restrict__ pairs,
              const int* __restrict__ bucket_base,
              int* __restrict__ rowptr, int* __restrict__ colid,
              float* __restrict__ dinv, int n) {
    __shared__ int hist[256];
    __shared__ int offs[256];
    __shared__ int rank[256];
    __shared__ int lbuf[CAP];
    int b = blockIdx.x, t = threadIdx.x;
    int beg = bucket_base[b], end = bucket_base[b + 1];
    int cnt = end - beg;
    hist[t] = 0; rank[t] = 0;
    __syncthreads();
    for (int i = t; i < cnt; i += 256) {
        int d = (int)(pairs[beg + i] >> 32);
        atomicAdd(&hist[d & 255], 1);
    }
    __syncthreads();
    int v = hist[t];
    offs[t] = v;
    __syncthreads();
    for (int off = 1; off < 256; off <<= 1) {
        int u = (t >= off) ? offs[t - off] : 0;
        __syncthreads();
        offs[t] += u;
        __syncthreads();
    }
    int ex = (t == 0) ? 0 : offs[t - 1];
    int node = (b << 8) + t;
    if (node < n) {
        rowptr[node] = beg + ex;
        dinv[node] = rsqrtf((float)v + 1.0f);
    } else if (node == n) {
        rowptr[n] = beg + ex;
    }
    __syncthreads();
    offs[t] = ex;
    __syncthreads();
    for (int i = t; i < cnt; i += 256) {
        unsigned long long p = pairs[beg + i];
        int d = (int)(p >> 32) & 255;
        int s = (int)(p & 0xffffffffu);
        int r = atomicAdd(&rank[d], 1);
        lbuf[offs[d] + r] = s;
    }
    __syncthreads();
    for (int i = t; i < cnt; i += 256) colid[beg + i] = lbuf[i];
}

// ---------------- concat helpers ----------------

__global__ void concat_kernel(const float4* __restrict__ f, const float4* __restrict__ c,
                              float4* __restrict__ A, int n) {
    int i = blockIdx.x * 256 + threadIdx.x;
    int total = n * 40;
    if (i < total) {
        int row = i / 40, j = i % 40;
        A[i] = (j < 32) ? f[row * 32 + j] : c[row * 8 + (j - 32)];
    }
}

__global__ void condcopy_kernel(const float4* __restrict__ c, float4* __restrict__ A, int n) {
    int i = blockIdx.x * 256 + threadIdx.x;
    if (i < n * 8) {
        int row = i / 8, j = i % 8;
        A[row * 24 + 16 + j] = c[row * 8 + j];
    }
}

// ---------------- GEMM: Y16[n][OUT] = fp16( (X[n][K] @ W[K][OUT]) * dinv[row] ) ----------------

template <int OUT>
__global__ __launch_bounds__(256)
void gemm_kernel(const float* __restrict__ X, int ldx, int K,
                 const float* __restrict__ W,
                 const float* __restrict__ dinv,
                 __half* __restrict__ Y, int n) {
    constexpr int TN = (OUT == 128) ? 8 : 4;
    __shared__ float As[32][64];
    __shared__ float Bs[32][OUT];
    const int t = threadIdx.x;
    const int tx = t & 15;
    const int ty = t >> 4;
    const int row0 = blockIdx.x * 64;

    float acc[4][TN];
#pragma unroll
    for (int r = 0; r < 4; r++)
#pragma unroll
        for (int c = 0; c < TN; c++) acc[r][c] = 0.f;

    const int ar = t >> 3;
    const int ak = (t & 7) << 2;

    for (int kt = 0; kt < K; kt += 32) {
#pragma unroll
        for (int i = 0; i < 2; i++) {
            int rr = ar + i * 32;
            int rg = row0 + rr;
            float4 v = make_float4(0.f, 0.f, 0.f, 0.f);
            if (rg < n) v = *(const float4*)(X + (size_t)rg * ldx + kt + ak);
            As[ak + 0][rr] = v.x; As[ak + 1][rr] = v.y;
            As[ak + 2][rr] = v.z; As[ak + 3][rr] = v.w;
        }
        constexpr int F4 = OUT / 4;
#pragma unroll
        for (int it = 0; it < (32 * F4) / 256; it++) {
            int idx = t + it * 256;
            int kr = idx / F4, c4 = (idx % F4) * 4;
            *(float4*)&Bs[kr][c4] = *(const float4*)(W + (size_t)(kt + kr) * OUT + c4);
        }
        __syncthreads();
#pragma unroll 4
        for (int k = 0; k < 32; k++) {
            const float4 a = *(const float4*)&As[k][ty << 2];
            const float4 b0 = *(const float4*)&Bs[k][tx << 2];
            float av[4] = {a.x, a.y, a.z, a.w};
            float bv[TN];
            bv[0] = b0.x; bv[1] = b0.y; bv[2] = b0.z; bv[3] = b0.w;
            if constexpr (OUT == 128) {
                const float4 b1 = *(const float4*)&Bs[k][64 + (tx << 2)];
                bv[4] = b1.x; bv[5] = b1.y; bv[6] = b1.z; bv[7] = b1.w;
            }
#pragma unroll
            for (int r = 0; r < 4; r++)
#pragma unroll
                for (int c = 0; c < TN; c++)
                    acc[r][c] = fmaf(av[r], bv[c], acc[r][c]);
        }
        __syncthreads();
    }
#pragma unroll
    for (int r = 0; r < 4; r++) {
        int rg = row0 + (ty << 2) + r;
        if (rg < n) {
            float di = dinv[rg];
            union { __half2 h2[2]; float2 f2; } u0;
            u0.h2[0] = __floats2half2_rn(acc[r][0] * di, acc[r][1] * di);
            u0.h2[1] = __floats2half2_rn(acc[r][2] * di, acc[r][3] * di);
            *(float2*)(Y + (size_t)rg * OUT + (tx << 2)) = u0.f2;
            if constexpr (OUT == 128) {
                union { __half2 h2[2]; float2 f2; } u1;
                u1.h2[0] = __floats2half2_rn(acc[r][4] * di, acc[r][5] * di);
                u1.h2[1] = __floats2half2_rn(acc[r][6] * di, acc[r][7] * di);
                *(float2*)(Y + (size_t)rg * OUT + 64 + (tx << 2)) = u1.f2;
            }
        }
    }
}

// ---------------- propagation (fp16 gather, fp32 accumulate) ----------------

template <int OUT, bool TANH>
__global__ __launch_bounds__(256)
void prop_kernel(const __half* __restrict__ hs, const float* __restrict__ dinv,
                 const int* __restrict__ rowptr, const int* __restrict__ colid,
                 const float* __restrict__ bias,
                 float* __restrict__ out, int ldo, int n) {
    int wave = threadIdx.x >> 6;
    int lane = threadIdx.x & 63;
    int node = blockIdx.x * 4 + wave;
    if (node >= n) return;
    int beg = rowptr[node], end = rowptr[node + 1];

    if constexpr (OUT == 128) {
        const __half2* base = (const __half2*)hs;
        float2 self = __half22float2(base[(size_t)node * 64 + lane]);
        float accx = self.x, accy = self.y;
        float accx2 = 0.f, accy2 = 0.f;
        int e = beg;
        for (; e + 8 <= end; e += 8) {
            int s[8];
#pragma unroll
            for (int j = 0; j < 8; j++) s[j] = colid[e + j];
            __half2 v[8];
#pragma unroll
            for (int j = 0; j < 8; j++) v[j] = base[(size_t)s[j] * 64 + lane];
#pragma unroll
            for (int j = 0; j < 8; j += 2) {
                float2 f0 = __half22float2(v[j]);
                float2 f1 = __half22float2(v[j + 1]);
                accx += f0.x; accy += f0.y;
                accx2 += f1.x; accy2 += f1.y;
            }
        }
        if (e + 4 <= end) {
            int s[4];
#pragma unroll
            for (int j = 0; j < 4; j++) s[j] = colid[e + j];
            __half2 v[4];
#pragma unroll
            for (int j = 0; j < 4; j++) v[j] = base[(size_t)s[j] * 64 + lane];
            float2 f0 = __half22float2(v[0]), f1 = __half22float2(v[1]);
            float2 f2 = __half22float2(v[2]), f3 = __half22float2(v[3]);
            accx += f0.x + f2.x; accy += f0.y + f2.y;
            accx2 += f1.x + f3.x; accy2 += f1.y + f3.y;
            e += 4;
        }
        for (; e < end; e++) {
            float2 f = __half22float2(base[(size_t)colid[e] * 64 + lane]);
            accx += f.x; accy += f.y;
        }
        accx += accx2; accy += accy2;
        float di = dinv[node];
        float ox = di * accx + bias[2 * lane];
        float oy = di * accy + bias[2 * lane + 1];
        if (TANH) { ox = tanhf(ox); oy = tanhf(oy); }
        *(float2*)(out + (size_t)node * ldo + 2 * lane) = make_float2(ox, oy);
    } else {
        float acc = __half2float(hs[(size_t)node * 64 + lane]);
        float acc2 = 0.f;
        int e = beg;
        for (; e + 8 <= end; e += 8) {
            int s[8];
#pragma unroll
            for (int j = 0; j < 8; j++) s[j] = colid[e + j];
            __half v[8];
#pragma unroll
            for (int j = 0; j < 8; j++) v[j] = hs[(size_t)s[j] * 64 + lane];
#pragma unroll
            for (int j = 0; j < 8; j += 2) {
                acc += __half2float(v[j]);
                acc2 += __half2float(v[j + 1]);
            }
        }
        if (e + 4 <= end) {
            int s[4];
#pragma unroll
            for (int j = 0; j < 4; j++) s[j] = colid[e + j];
            __half v[4];
#pragma unroll
            for (int j = 0; j < 4; j++) v[j] = hs[(size_t)s[j] * 64 + lane];
            acc += __half2float(v[0]) + __half2float(v[2]);
            acc2 += __half2float(v[1]) + __half2float(v[3]);
            e += 4;
        }
        for (; e < end; e++) acc += __half2float(hs[(size_t)colid[e] * 64 + lane]);
        acc += acc2;
        float v = dinv[node] * acc + bias[lane];
        if (TANH) v = tanhf(v);
        out[(size_t)node * ldo + lane] = v;
    }
}

// ---------------- launch ----------------

extern "C" void kernel_launch(void* const* d_in, const int* in_sizes, int n_in,
                              void* d_out, int out_size, void* d_ws, size_t ws_size,
                              hipStream_t stream) {
    const int n = NN, E = NE;
    const float* feature   = (const float*)d_in[0];
    const float* condition = (const float*)d_in[1];
    const int*   ei        = (const int*)d_in[2];
    const float* W_e1 = (const float*)d_in[3];  const float* b_e1 = (const float*)d_in[4];
    const float* W_e2 = (const float*)d_in[5];  const float* b_e2 = (const float*)d_in[6];
    const float* W_e3 = (const float*)d_in[7];  const float* b_e3 = (const float*)d_in[8];
    const float* W_d1 = (const float*)d_in[9];  const float* b_d1 = (const float*)d_in[10];
    const float* W_d2 = (const float*)d_in[11]; const float* b_d2 = (const float*)d_in[12];
    const float* W_d3 = (const float*)d_in[13]; const float* b_d3 = (const float*)d_in[14];
    float* out = (float*)d_out;

    float*  A    = (float*)d_ws;                    // n*160 floats
    __half* H16  = (__half*)(A + (size_t)n * 160);  // n*128 halves
    float*  dinv = (float*)(H16 + (size_t)n * 128); // n
    int* rowptr  = (int*)(dinv + n);                // n+1
    int* colid   = rowptr + n + 1;                  // E
    uintptr_t pp = (uintptr_t)(colid + E);
    pp = (pp + 7) & ~(uintptr_t)7;
    unsigned long long* pairs = (unsigned long long*)pp;  // E
    int* bucket_cnt  = (int*)(pairs + E);           // 512
    int* bucket_base = bucket_cnt + 512;            // NB+1
    int* bucket_fill = bucket_base + 512;           // NB

    hipMemsetAsync(bucket_cnt, 0, 512 * sizeof(int), stream);

    int nbc = (E + CHUNK - 1) / CHUNK;  // 196
    coarse_hist<<<nbc, 256, 0, stream>>>(ei, bucket_cnt, E);
    scan_buckets<<<1, 512, 0, stream>>>(bucket_cnt, bucket_base, bucket_fill);
    coarse_scatter<<<nbc, 256, 0, stream>>>(ei, bucket_fill, pairs, E);
    fine_csr<<<NB, 256, 0, stream>>>(pairs, bucket_base, rowptr, colid, dinv, n);

    concat_kernel<<<(n * 40 + 255) / 256, 256, 0, stream>>>(
        (const float4*)feature, (const float4*)condition, (float4*)A, n);

    int gt = (n + 63) / 64;
    int pb = (n + 3) / 4;

    // encoder
    gemm_kernel<128><<<gt, 256, 0, stream>>>(A, 160, 160, W_e1, dinv, H16, n);
    prop_kernel<128, true><<<pb, 256, 0, stream>>>(H16, dinv, rowptr, colid, b_e1, A, 128, n);
    gemm_kernel<128><<<gt, 256, 0, stream>>>(A, 128, 128, W_e2, dinv, H16, n);
    prop_kernel<128, true><<<pb, 256, 0, stream>>>(H16, dinv, rowptr, colid, b_e2, A, 128, n);
    gemm_kernel<64><<<gt, 256, 0, stream>>>(A, 128, 128, W_e3, dinv, H16, n);
    prop_kernel<64, false><<<pb, 256, 0, stream>>>(H16, dinv, rowptr, colid, b_e3, A, 96, n);
    condcopy_kernel<<<(n * 8 + 255) / 256, 256, 0, stream>>>(
        (const float4*)condition, (float4*)A, n);

    // decoder
    gemm_kernel<128><<<gt, 256, 0, stream>>>(A, 96, 96, W_d1, dinv, H16, n);
    prop_kernel<128, true><<<pb, 256, 0, stream>>>(H16, dinv, rowptr, colid, b_d1, A, 128, n);
    gemm_kernel<128><<<gt, 256, 0, stream>>>(A, 128, 128, W_d2, dinv, H16, n);
    prop_kernel<128, true><<<pb, 256, 0, stream>>>(H16, dinv, rowptr, colid, b_d2, A, 128, n);
    gemm_kernel<128><<<gt, 256, 0, stream>>>(A, 128, 128, W_d3, dinv, H16, n);
    prop_kernel<128, false><<<pb, 256, 0, stream>>>(H16, dinv, rowptr, colid, b_d3, out, 128, n);
}